// Round 2
// baseline (210.809 us; speedup 1.0000x reference)
//
#include <hip/hip_runtime.h>
#include <hip/hip_bf16.h>

// ============================================================================
// fused stride-2 "transposed conv" + bias + channel-softmax + sigmoid
//
// PAD==OUT_PAD==1 => odd h or odd w outputs are the constant vector
// sigmoid(2*softmax(bias)). Even-even outputs are a dense 4x4 conv:
//   O[n,c,p,q] = sum_{ic,kh,kw} x[n,ic,p-kh,q-kw]*W[c,ic,kh,kw]
//
// Numerics: bf16 hi/lo split (3 MFMA terms: Whi*Xhi + Wlo*Xhi + Whi*Xlo).
// R2: two-pass X staging (hi pass then lo pass, same 26.75KB buffer) +
// in-register softmax => LDS 68.6KB -> 27KB, occupancy 2 -> 4 blocks/CU.
// ============================================================================

typedef __bf16 bf16x8 __attribute__((ext_vector_type(8)));
typedef float  f32x4  __attribute__((ext_vector_type(4)));
typedef unsigned short ushort_t;

#define TILE_P 8
#define TILE_Q 16
#define PATCH_R 11                 // TILE_P + 3
#define PATCH_C 19                 // TILE_Q + 3
#define XELEMS (PATCH_R*PATCH_C*64)   // 13376 bf16 in the single staged plane
#define SMEM_BYTES 27648              // 26752 X plane (+ overlay reduce bufs)
#define WSW_BYTES (16*8*2*2*64*16)    // 524288: [tap][ct8][ch2][hi/lo][lane64][16B]

// ---- prep: weight -> MFMA-fragment-ordered bf16 hi/lo in workspace ----------
// A-frag (16x16x32, M=cout,K=ic): lane l holds A[row=l&15][k=(l>>4)*8+i], i<8.
__global__ void prep_w_kernel(const float* __restrict__ w, ushort_t* __restrict__ wsW) {
    int slot = blockIdx.x * 256 + threadIdx.x;      // 16384 slots
    int lane = slot & 63;
    int ch   = (slot >> 6) & 1;
    int ct   = (slot >> 7) & 7;
    int tap  = slot >> 10;
    int kh = tap >> 2, kw = tap & 3;
    int cout = ct * 16 + (lane & 15);
    bf16x8 hi, lo;
#pragma unroll
    for (int i = 0; i < 8; ++i) {
        int ic = ch * 32 + (lane >> 4) * 8 + i;
        float v = w[((cout * 64 + ic) * 4 + kh) * 4 + kw];
        __bf16 h = (__bf16)v;
        hi[i] = h;
        lo[i] = (__bf16)(v - (float)h);
    }
    bf16x8* wf = (bf16x8*)wsW;
    int off = (((tap * 8 + ct) * 2 + ch) * 2) * 64 + lane;  // hi block
    wf[off]      = hi;
    wf[off + 64] = lo;
}

// ---- prep: const vector sigmoid(2*softmax(bias)) ---------------------------
__global__ void prep_const_kernel(const float* __restrict__ bias, float* __restrict__ wsc) {
    __shared__ float red[128];
    int t = threadIdx.x;
    red[t] = bias[t];
    __syncthreads();
    float m = -3.4e38f;
    for (int i = 0; i < 128; ++i) m = fmaxf(m, red[i]);
    float e = __expf(red[t] - m);
    __syncthreads();
    red[t] = e;
    __syncthreads();
    float s = 0.f;
    for (int i = 0; i < 128; ++i) s += red[i];
    float v = e / s;
    wsc[t] = 1.0f / (1.0f + __expf(-2.0f * v));
}

// ---- stage one plane of the X patch (hi pass or lo pass) -------------------
__device__ __forceinline__ void stage_x(const float* __restrict__ xg,
                                        ushort_t* __restrict__ xp,
                                        int p0, int q0, int tid, bool lo_pass) {
    for (int grp = tid; grp < PATCH_R * PATCH_C * 8; grp += 256) {
        int r   = grp / (PATCH_C * 8);
        int rem = grp - r * (PATCH_C * 8);
        int c   = rem >> 3;
        int g   = rem & 7;
        int row = p0 + r - 3;
        int col = q0 + c - 3;
        bool ok = (row >= 0) & (row < 64) & (col >= 0) & (col < 64);
        const float* src = xg + ((g * 8) << 12) + (row << 6) + col;  // ic stride 4096
        bf16x8 v;
#pragma unroll
        for (int i = 0; i < 8; ++i) {
            float f = ok ? src[i << 12] : 0.0f;
            __bf16 h = (__bf16)f;
            v[i] = lo_pass ? (__bf16)(f - (float)h) : h;
        }
        int slot = ((r * PATCH_C + c) * 8 + (g ^ (c & 7))) * 8;     // elem index
        *(bf16x8*)(xp + slot) = v;
    }
}

// ---- main: conv(MFMA, 2 passes) + in-register softmax + sigmoid ------------
__launch_bounds__(256, 4)
__global__ void conv_main_kernel(const float* __restrict__ x,
                                 const float* __restrict__ bias,
                                 const ushort_t* __restrict__ wsW,
                                 const float* __restrict__ wsc,
                                 float* __restrict__ out) {
    extern __shared__ char smem[];
    ushort_t* xp = (ushort_t*)smem;

    const int tid = threadIdx.x;
    const int n   = blockIdx.z;
    const int p0  = blockIdx.y * TILE_P;
    const int q0  = blockIdx.x * TILE_Q;

    const int lane = tid & 63;
    const int wv   = tid >> 6;       // wave id: cout tiles 2*wv, 2*wv+1
    const int ltc  = lane & 15;      // B/D col (position q index)
    const int lg   = lane >> 4;      // k-group / D row-group

    const float* xg = x + (size_t)n * 64 * 64 * 64;
    const bf16x8* wf = (const bf16x8*)wsW;

    f32x4 acc[2][8];
#pragma unroll
    for (int ct = 0; ct < 2; ++ct)
#pragma unroll
        for (int pt = 0; pt < 8; ++pt)
            acc[ct][pt] = (f32x4){0.f, 0.f, 0.f, 0.f};

    // ================= pass 1: B = X_hi  (Whi*Xhi + Wlo*Xhi) =================
    stage_x(xg, xp, p0, q0, tid, false);
    __syncthreads();

    for (int tap = 0; tap < 16; ++tap) {
        int kh = tap >> 2, kw = tap & 3;
        int cc = ltc + 3 - kw;       // patch col for this lane
        int c7 = cc & 7;
        int rb = 3 - kh;             // patch row base (pt adds 1 per row)
#pragma unroll
        for (int ch = 0; ch < 2; ++ch) {
            int a0 = (((tap * 8 + wv * 2 + 0) * 2 + ch) * 2) * 64 + lane;
            int a1 = (((tap * 8 + wv * 2 + 1) * 2 + ch) * 2) * 64 + lane;
            bf16x8 ahi0 = wf[a0], alo0 = wf[a0 + 64];
            bf16x8 ahi1 = wf[a1], alo1 = wf[a1 + 64];
            int g4 = ((ch << 2) | lg) ^ c7;
            int base = ((rb * PATCH_C + cc) * 8 + g4) * 8;  // elems; +1216/row
            const ushort_t* hp = xp + base;
#pragma unroll
            for (int pt = 0; pt < 8; ++pt) {
                bf16x8 bhi = *(const bf16x8*)(hp + pt * (PATCH_C * 64));
                acc[0][pt] = __builtin_amdgcn_mfma_f32_16x16x32_bf16(ahi0, bhi, acc[0][pt], 0, 0, 0);
                acc[0][pt] = __builtin_amdgcn_mfma_f32_16x16x32_bf16(alo0, bhi, acc[0][pt], 0, 0, 0);
                acc[1][pt] = __builtin_amdgcn_mfma_f32_16x16x32_bf16(ahi1, bhi, acc[1][pt], 0, 0, 0);
                acc[1][pt] = __builtin_amdgcn_mfma_f32_16x16x32_bf16(alo1, bhi, acc[1][pt], 0, 0, 0);
            }
        }
    }
    __syncthreads();   // pass-1 reads done; safe to overwrite xp

    // ================= pass 2: B = X_lo  (Whi*Xlo) ===========================
    stage_x(xg, xp, p0, q0, tid, true);
    __syncthreads();

    for (int tap = 0; tap < 16; ++tap) {
        int kh = tap >> 2, kw = tap & 3;
        int cc = ltc + 3 - kw;
        int c7 = cc & 7;
        int rb = 3 - kh;
#pragma unroll
        for (int ch = 0; ch < 2; ++ch) {
            int a0 = (((tap * 8 + wv * 2 + 0) * 2 + ch) * 2) * 64 + lane;
            int a1 = (((tap * 8 + wv * 2 + 1) * 2 + ch) * 2) * 64 + lane;
            bf16x8 ahi0 = wf[a0];
            bf16x8 ahi1 = wf[a1];
            int g4 = ((ch << 2) | lg) ^ c7;
            int base = ((rb * PATCH_C + cc) * 8 + g4) * 8;
            const ushort_t* lp = xp + base;
#pragma unroll
            for (int pt = 0; pt < 8; ++pt) {
                bf16x8 blo = *(const bf16x8*)(lp + pt * (PATCH_C * 64));
                acc[0][pt] = __builtin_amdgcn_mfma_f32_16x16x32_bf16(ahi0, blo, acc[0][pt], 0, 0, 0);
                acc[1][pt] = __builtin_amdgcn_mfma_f32_16x16x32_bf16(ahi1, blo, acc[1][pt], 0, 0, 0);
            }
        }
    }
    __syncthreads();   // pass-2 reads done; xp region free for reduce overlay

    // ========== bias add, then in-register channel softmax ===================
    // D layout per wave: position = (pt, ltc); channels = wv*32 + ct*16 + lg*4 + r
    float* red1 = (float*)smem;            // [128 pos][4 waves]
    float* red2 = (float*)(smem + 2048);   // [128 pos][4 waves]

    {
        f32x4 bv[2];
#pragma unroll
        for (int ct = 0; ct < 2; ++ct)
#pragma unroll
            for (int r = 0; r < 4; ++r)
                bv[ct][r] = bias[wv * 32 + ct * 16 + lg * 4 + r];
#pragma unroll
        for (int ct = 0; ct < 2; ++ct)
#pragma unroll
            for (int pt = 0; pt < 8; ++pt)
                acc[ct][pt] += bv[ct];
    }

    // per-position max over this wave's 32 channels
    float wm[8];
#pragma unroll
    for (int pt = 0; pt < 8; ++pt) {
        f32x4 a = acc[0][pt], b = acc[1][pt];
        float m = fmaxf(fmaxf(fmaxf(a[0], a[1]), fmaxf(a[2], a[3])),
                        fmaxf(fmaxf(b[0], b[1]), fmaxf(b[2], b[3])));
        m = fmaxf(m, __shfl_xor(m, 16));
        m = fmaxf(m, __shfl_xor(m, 32));
        wm[pt] = m;
    }
    if (lg == 0) {
#pragma unroll
        for (int pt = 0; pt < 8; ++pt)
            red1[(pt * 16 + ltc) * 4 + wv] = wm[pt];
    }
    __syncthreads();

    float gm[8];
#pragma unroll
    for (int pt = 0; pt < 8; ++pt) {
        f32x4 v = *(f32x4*)&red1[(pt * 16 + ltc) * 4];
        gm[pt] = fmaxf(fmaxf(v[0], v[1]), fmaxf(v[2], v[3]));
    }

    // exp (overwrite acc) + per-position sum
    float ws[8];
#pragma unroll
    for (int pt = 0; pt < 8; ++pt) {
        float s = 0.f;
#pragma unroll
        for (int ct = 0; ct < 2; ++ct) {
            f32x4 e;
#pragma unroll
            for (int r = 0; r < 4; ++r) {
                e[r] = __expf(acc[ct][pt][r] - gm[pt]);
                s += e[r];
            }
            acc[ct][pt] = e;
        }
        s += __shfl_xor(s, 16);
        s += __shfl_xor(s, 32);
        ws[pt] = s;
    }
    if (lg == 0) {
#pragma unroll
        for (int pt = 0; pt < 8; ++pt)
            red2[(pt * 16 + ltc) * 4 + wv] = ws[pt];
    }
    __syncthreads();

    float inv[8];
#pragma unroll
    for (int pt = 0; pt < 8; ++pt) {
        f32x4 v = *(f32x4*)&red2[(pt * 16 + ltc) * 4];
        inv[pt] = 1.0f / (v[0] + v[1] + v[2] + v[3]);
    }

    // ========== sigmoid + stores (even-h rows; const odd-w partner) ==========
    float cv[2][4];
#pragma unroll
    for (int ct = 0; ct < 2; ++ct)
#pragma unroll
        for (int r = 0; r < 4; ++r)
            cv[ct][r] = wsc[wv * 32 + ct * 16 + lg * 4 + r];

    int q = q0 + ltc;
    if (q < 65) {
#pragma unroll
        for (int pt = 0; pt < 8; ++pt) {
            int p = p0 + pt;
            if (p < 65) {
#pragma unroll
                for (int ct = 0; ct < 2; ++ct) {
                    int c = wv * 32 + ct * 16 + lg * 4;
#pragma unroll
                    for (int r = 0; r < 4; ++r) {
                        float v  = acc[ct][pt][r] * inv[pt];
                        float sg = 1.0f / (1.0f + __expf(-2.0f * v));
                        size_t o = (((size_t)(n * 128 + c + r) * 129) + 2 * p) * 129 + 2 * q;
                        out[o] = sg;
                        if (q < 64) out[o + 1] = cv[ct][r];
                    }
                }
            }
        }
    }
}

// ---- fill: odd-h rows are the constant vector ------------------------------
__global__ void fill_kernel(const float* __restrict__ wsc, float* __restrict__ out) {
    int rid  = blockIdx.x * 4 + (threadIdx.x >> 6);   // row id: [n][c][oh]
    int lane = threadIdx.x & 63;
    int n   = rid >> 13;            // /8192
    int rem = rid & 8191;
    int c   = rem >> 6;
    int oh  = ((rem & 63) << 1) + 1;
    float v = wsc[c];
    size_t base = ((size_t)(n * 128 + c) * 129 + oh) * 129;
    out[base + lane]      = v;
    out[base + 64 + lane] = v;
    if (lane == 0) out[base + 128] = v;
}

extern "C" void kernel_launch(void* const* d_in, const int* in_sizes, int n_in,
                              void* d_out, int out_size, void* d_ws, size_t ws_size,
                              hipStream_t stream) {
    const float* x    = (const float*)d_in[0];
    const float* w    = (const float*)d_in[1];
    const float* bias = (const float*)d_in[2];
    float* out = (float*)d_out;

    ushort_t* wsW = (ushort_t*)d_ws;                          // 512 KB
    float* wsc    = (float*)((char*)d_ws + WSW_BYTES);        // 512 B

    (void)hipFuncSetAttribute((const void*)conv_main_kernel,
                              hipFuncAttributeMaxDynamicSharedMemorySize, SMEM_BYTES);

    prep_w_kernel<<<64, 256, 0, stream>>>(w, wsW);
    prep_const_kernel<<<1, 128, 0, stream>>>(bias, wsc);

    dim3 grid(5, 9, 32);   // q-tiles, p-tiles, n
    conv_main_kernel<<<grid, 256, SMEM_BYTES, stream>>>(x, bias, wsW, wsc, out);

    fill_kernel<<<65536, 256, 0, stream>>>(wsc, out);
}